// Round 4
// baseline (347.118 us; speedup 1.0000x reference)
//
#include <hip/hip_runtime.h>
#include <math.h>
#include <stdint.h>

// VectorQuantizer on MI355X (gfx950). N=131072, D=64, K=2048, fp32.
// bf16 MFMA approx scores (error-bounded) -> margin-pruned exact fp32 rescore.
// out: [N*D] quantized_st | [1] loss | [N] idx (as float)
//
// Round-4 restructure (post-mortem: round 3 was LDS-pipe-bound, MfmaUtil 11%):
//  - R=4 row-groups per wave: 2 A-frag ds_reads feed 8 MFMAs (was 3 reads : 2).
//  - C-init = hoisted zero quad; -0.5*en2 dropped from approx score (en rows are
//    unit vectors, |en2-1| < 1e-6 absorbed by MARGIN). Exact rescore unchanged.
//  - 4 waves x 64 rows = 256 rows/block, 512 blocks; xn stride 65 (bank spread).
//
// ws: [0] double partials[512] | [8192] f32 en2[K] | [16384] f32 en[K*64]
//     | [540672] u32 frags[K*32]  (total ~784 KB)

#define D 64
#define EPS 1e-12f
#define WPB 4              // waves per block
#define RG 4               // row-groups (16 rows each) per wave
#define RPW (RG * 16)      // 64 rows per wave
#define RPB (WPB * RPW)    // 256 rows per block
#define CHUNK_TILES 16     // tiles per staged chunk (32 KB)
#define CAND_CAP 480       // per-wave candidate cap (7.5/row, same ratio as r3)
#define MARGIN 0.010f      // > 2*bf16 err (worst 8e-3) + en2 slack 1e-6

typedef short bf16x8 __attribute__((ext_vector_type(8)));
typedef float f32x4 __attribute__((ext_vector_type(4)));

__device__ __forceinline__ uint32_t f2bf(float f) {   // RNE f32->bf16 (finite)
    uint32_t u = __builtin_bit_cast(uint32_t, f);
    return (u + 0x7FFFu + ((u >> 16) & 1u)) >> 16;
}

// ---------------- Kernel A: normalize codebook (bit-exact vs round 3) -------
__global__ __launch_bounds__(256) void vq_norm_emb(const float* __restrict__ emb,
                                                   float* __restrict__ en,
                                                   float* __restrict__ en2,
                                                   int K) {
    int wave = (int)((blockIdx.x * blockDim.x + threadIdx.x) >> 6);
    int lane = threadIdx.x & 63;
    if (wave >= K) return;
    float v = emb[(size_t)wave * D + lane];
    float s = v * v;
    #pragma unroll
    for (int m = 32; m >= 1; m >>= 1) s += __shfl_xor(s, m, 64);
    float e = v / fmaxf(sqrtf(s), EPS);
    float s2 = e * e;
    #pragma unroll
    for (int m = 32; m >= 1; m >>= 1) s2 += __shfl_xor(s2, m, 64);
    en[(size_t)wave * D + lane] = e;
    if (lane == 0) en2[wave] = s2;
}

// ---------------- Kernel A2: build bf16 A-fragments (layout verified r3) ----
// code = t*16 + (l&15), dims = h*32 + (l>>4)*8 + j. 16 B/lane contiguous.
__global__ __launch_bounds__(256) void vq_build_frags(const float* __restrict__ en,
                                                      uint32_t* __restrict__ frags,
                                                      int K) {
    int t = (int)(blockIdx.x * blockDim.x + threadIdx.x);
    int tile = t >> 6, lane = t & 63;
    if (tile >= K / 16) return;
    int code = tile * 16 + (lane & 15);
    int dbase = (lane >> 4) * 8;
    #pragma unroll
    for (int h = 0; h < 2; ++h) {
        const float* p = en + (size_t)code * D + h * 32 + dbase;
        uint4 u;
        u.x = f2bf(p[0]) | (f2bf(p[1]) << 16);
        u.y = f2bf(p[2]) | (f2bf(p[3]) << 16);
        u.z = f2bf(p[4]) | (f2bf(p[5]) << 16);
        u.w = f2bf(p[6]) | (f2bf(p[7]) << 16);
        *(uint4*)(frags + ((size_t)(tile * 2 + h) * 64 + lane) * 4) = u;
    }
}

// ---------------- Kernel B: main ----------------
__global__ __launch_bounds__(256) void vq_main(const float* __restrict__ x,
                                               const float* __restrict__ en,
                                               const float* __restrict__ en2g,
                                               const uint32_t* __restrict__ frags,
                                               float* __restrict__ out_q,
                                               float* __restrict__ out_idx,
                                               double* __restrict__ partials,
                                               int N, int K) {
    __shared__ float xn[RPB * 65];                                   // 66.6 KB, stride 65
    __shared__ __align__(16) uint32_t fragbuf[2][CHUNK_TILES * 512]; // 2 x 32 KB
    __shared__ uint32_t cand[WPB][CAND_CAP];                         // 7.7 KB
    __shared__ int candcnt[WPB];
    __shared__ unsigned long long keys[RPB];                         // 2 KB
    __shared__ double red[WPB];

    const int tid = (int)threadIdx.x;
    const int w = tid >> 6, lane = tid & 63;
    const int rowbase = (int)blockIdx.x * RPB;
    const int NT = K / 16;                    // 128 tiles
    const int NC = NT / CHUNK_TILES;          // 8 chunks

    // ---- phase 0: load + normalize rows (bit-exact arithmetic vs r3) ----
    for (int r = 0; r < RPW; ++r) {
        int rb = w * RPW + r;
        float v = x[(size_t)(rowbase + rb) * D + lane];
        float s = v * v;
        #pragma unroll
        for (int m = 32; m >= 1; m >>= 1) s += __shfl_xor(s, m, 64);
        xn[rb * 65 + lane] = v / fmaxf(sqrtf(s), EPS);
    }
    for (int i = tid; i < RPB; i += WPB * 64) keys[i] = ~0ull;
    if (lane == 0) candcnt[w] = 0;
    __syncthreads();

    // ---- B-fragments in registers: group g -> rows w*64 + g*16 + (l&15) ----
    bf16x8 bfr[RG][2];
    #pragma unroll
    for (int g = 0; g < RG; ++g)
        #pragma unroll
        for (int h = 0; h < 2; ++h) {
            const float* p = &xn[(w * RPW + g * 16 + (lane & 15)) * 65 +
                                 h * 32 + ((lane >> 4) * 8)];
            union { uint32_t u[4]; bf16x8 v; } cvt;
            cvt.u[0] = f2bf(p[0]) | (f2bf(p[1]) << 16);
            cvt.u[1] = f2bf(p[2]) | (f2bf(p[3]) << 16);
            cvt.u[2] = f2bf(p[4]) | (f2bf(p[5]) << 16);
            cvt.u[3] = f2bf(p[6]) | (f2bf(p[7]) << 16);
            bfr[g][h] = cvt.v;
        }

    const f32x4 zero4 = {0.f, 0.f, 0.f, 0.f};   // hoisted MFMA C-init
    float Rmax[RG];
    #pragma unroll
    for (int g = 0; g < RG; ++g) Rmax[g] = -3.0e38f;
    float tau[RG];
    const float4* frags4 = (const float4*)frags;

    // ---- pass 0: row maxima of approx score S = dot_bf16; pass 1: collect ---
    for (int pass = 0; pass < 2; ++pass) {
        if (pass == 1) {
            #pragma unroll
            for (int g = 0; g < RG; ++g) {
                float r1 = fmaxf(Rmax[g], __shfl_xor(Rmax[g], 16, 64));
                tau[g] = fmaxf(r1, __shfl_xor(r1, 32, 64)) - MARGIN;
            }
        }
        // prologue: stage chunk 0 into buf 0
        float4 st[8];
        #pragma unroll
        for (int i = 0; i < 8; ++i) st[i] = frags4[tid + i * 256];
        #pragma unroll
        for (int i = 0; i < 8; ++i) *(float4*)&fragbuf[0][(tid + i * 256) * 4] = st[i];
        __syncthreads();

        int buf = 0;
        for (int c = 0; c < NC; ++c) {
            if (c + 1 < NC) {                  // prefetch next chunk into regs
                #pragma unroll
                for (int i = 0; i < 8; ++i)
                    st[i] = frags4[(size_t)(c + 1) * 2048 + tid + i * 256];
            }
            #pragma unroll 2
            for (int tl = 0; tl < CHUNK_TILES; ++tl) {
                int t = c * CHUNK_TILES + tl;
                int cb = t * 16 + ((lane >> 4) << 2);
                bf16x8 a0 = *(const bf16x8*)&fragbuf[buf][(tl * 2 + 0) * 256 + lane * 4];
                bf16x8 a1 = *(const bf16x8*)&fragbuf[buf][(tl * 2 + 1) * 256 + lane * 4];
                f32x4 acc[RG];
                #pragma unroll
                for (int g = 0; g < RG; ++g) {
                    acc[g] = __builtin_amdgcn_mfma_f32_16x16x32_bf16(a0, bfr[g][0], zero4, 0, 0, 0);
                    acc[g] = __builtin_amdgcn_mfma_f32_16x16x32_bf16(a1, bfr[g][1], acc[g], 0, 0, 0);
                }
                if (pass == 0) {
                    #pragma unroll
                    for (int g = 0; g < RG; ++g) {
                        float m4 = fmaxf(fmaxf(acc[g][0], acc[g][1]),
                                         fmaxf(acc[g][2], acc[g][3]));
                        Rmax[g] = fmaxf(Rmax[g], m4);
                    }
                } else {
                    #pragma unroll
                    for (int g = 0; g < RG; ++g) {
                        float m4 = fmaxf(fmaxf(acc[g][0], acc[g][1]),
                                         fmaxf(acc[g][2], acc[g][3]));
                        if (__any(m4 >= tau[g])) {
                            #pragma unroll
                            for (int q = 0; q < 4; ++q) {
                                if (acc[g][q] >= tau[g]) {
                                    int slot = atomicAdd(&candcnt[w], 1);
                                    if (slot < CAND_CAP)
                                        cand[w][slot] = ((uint32_t)(cb + q) << 6) |
                                                        (uint32_t)(g * 16 + (lane & 15));
                                }
                            }
                        }
                    }
                }
            }
            if (c + 1 < NC) {                  // write prefetched chunk to other buf
                buf ^= 1;
                #pragma unroll
                for (int i = 0; i < 8; ++i)
                    *(float4*)&fragbuf[buf][(tid + i * 256) * 4] = st[i];
            }
            __syncthreads();
        }
    }

    // ---- phase 3: exact fp32 rescore (bit-identical arithmetic vs r3) ----
    int cnt = candcnt[w];
    cnt = cnt < CAND_CAP ? cnt : CAND_CAP;
    for (int base = 0; base < cnt; base += 64) {
        int i = base + lane;
        if (i < cnt) {
            uint32_t e = cand[w][i];
            int k = (int)(e >> 6), rloc = (int)(e & 63u);
            const float* ev = en + (size_t)k * D;
            const float* xv = &xn[(w * RPW + rloc) * 65];
            float dot = 0.f;
            #pragma unroll
            for (int d0 = 0; d0 < D; ++d0) dot = fmaf(xv[d0], ev[d0], dot);
            float R = fmaf(-0.5f, en2g[k], dot);
            uint32_t fb = __builtin_bit_cast(uint32_t, -R);   // minimize -R
            uint32_t ord = (fb & 0x80000000u) ? ~fb : (fb | 0x80000000u);
            unsigned long long key = ((unsigned long long)ord << 32) | (uint32_t)k;
            atomicMin(&keys[w * RPW + rloc], key);            // ties -> smaller k
        }
    }
    __syncthreads();

    // ---- phase 4: epilogue ----
    float ls = 0.f;
    for (int r = 0; r < RPW; ++r) {
        int rb = w * RPW + r;
        int k = (int)(keys[rb] & 0x7FFull);
        float rn = fmaxf(sqrtf(en2g[k]), EPS);
        float q = en[(size_t)k * D + lane] / rn;       // l2norm(en[k]) exactly
        float a = xn[rb * 65 + lane];
        float dx = q - a;
        ls = fmaf(dx, dx, ls);
        out_q[(size_t)(rowbase + rb) * D + lane] = a + dx;   // xn + (quantized - xn)
    }
    if (lane < RPW) out_idx[rowbase + w * RPW + lane] =
        (float)(int)(keys[w * RPW + lane] & 0x7FFull);
    #pragma unroll
    for (int m = 32; m >= 1; m >>= 1) ls += __shfl_xor(ls, m, 64);
    if (lane == 0) red[w] = (double)ls;
    __syncthreads();
    if (tid == 0) {
        double s = 0.0;
        #pragma unroll
        for (int i = 0; i < WPB; ++i) s += red[i];
        partials[blockIdx.x] = s;
    }
}

// ---------------- Kernel C: finalize loss ----------------
__global__ __launch_bounds__(512) void vq_finalize(const double* __restrict__ partials,
                                                   int nb, float* __restrict__ loss_out,
                                                   int N) {
    __shared__ double red[512];
    int t = (int)threadIdx.x;
    double s = 0.0;
    for (int i = t; i < nb; i += 512) s += partials[i];
    red[t] = s;
    __syncthreads();
    #pragma unroll
    for (int off = 256; off >= 1; off >>= 1) {
        if (t < off) red[t] += red[t + off];
        __syncthreads();
    }
    if (t == 0) {
        double mean = red[0] / ((double)N * (double)D);
        loss_out[0] = (float)(mean * 1.25);   // q_loss + 0.25*e_loss (identical terms)
    }
}

extern "C" void kernel_launch(void* const* d_in, const int* in_sizes, int n_in,
                              void* d_out, int out_size, void* d_ws, size_t ws_size,
                              hipStream_t stream) {
    const float* x   = (const float*)d_in[0];
    const float* emb = (const float*)d_in[1];
    int N = in_sizes[0] / D;
    int K = in_sizes[1] / D;

    float* out      = (float*)d_out;
    float* out_q    = out;
    float* loss_out = out + (size_t)N * D;
    float* out_idx  = out + (size_t)N * D + 1;

    char* ws = (char*)d_ws;
    double*   partials = (double*)ws;                       // 8 KB reserved
    float*    en2      = (float*)(ws + 8192);               // 8 KB
    float*    en       = (float*)(ws + 16384);              // 512 KB
    uint32_t* frags    = (uint32_t*)(ws + 540672);          // 256 KB

    vq_norm_emb<<<(K + 3) / 4, 256, 0, stream>>>(emb, en, en2, K);
    vq_build_frags<<<(K / 16 * 64 + 255) / 256, 256, 0, stream>>>(en, frags, K);

    int nbB = N / RPB;   // 512
    vq_main<<<nbB, 256, 0, stream>>>(x, en, en2, frags, out_q, out_idx,
                                     partials, N, K);
    vq_finalize<<<1, 512, 0, stream>>>(partials, nbB, loss_out, N);
}

// Round 5
// 195.509 us; speedup vs baseline: 1.7755x; 1.7755x over previous
//
#include <hip/hip_runtime.h>
#include <math.h>
#include <stdint.h>

// VectorQuantizer on MI355X (gfx950). N=131072, D=64, K=2048, fp32.
// Round 5: single-pass streaming-threshold MFMA scoring, 4 waves/SIMD.
//  - r4 post-mortem: 142 KB LDS -> 1 wave/SIMD -> everything serialized.
//  - Now: LDS 40.5 KB -> 4 blocks/CU (16 waves/CU); A-frags direct from
//    L2-resident global (no fragbuf, no staging barriers); ONE scoring pass
//    with per-row running max threshold (margin-proof in comments).
// out: [N*D] quantized_st | [1] loss | [N] idx (as float)
// ws: [0] partials[1024] | [8192] en2[K] | [16384] en[K*64] | [540672] frags

#define D 64
#define EPS 1e-12f
#define WPB 4              // waves per block
#define RG 2               // row-groups (16 rows) per wave
#define RPW (RG * 16)      // 32 rows per wave
#define RPB (WPB * RPW)    // 128 rows per block
#define CAP 832            // u16 candidate entries per wave (E~352, huge slack)
#define MARGIN 0.010f      // > 2*delta; delta = bf16 dot err (<=3.9e-3) + 1e-6

typedef short bf16x8 __attribute__((ext_vector_type(8)));
typedef float f32x4 __attribute__((ext_vector_type(4)));

__device__ __forceinline__ uint32_t f2bf(float f) {   // RNE f32->bf16 (finite)
    uint32_t u = __builtin_bit_cast(uint32_t, f);
    return (u + 0x7FFFu + ((u >> 16) & 1u)) >> 16;
}
// xn LDS swizzle: float4-slot XOR by row&7 -> conflict-free frag/row access
__device__ __forceinline__ int xsw(int row, int d) {
    return row * 64 + ((((d >> 2) ^ (row & 7)) << 2) | (d & 3));
}

// ---------------- Kernel A: normalize codebook (bit-exact vs r3/r4) --------
__global__ __launch_bounds__(256) void vq_norm_emb(const float* __restrict__ emb,
                                                   float* __restrict__ en,
                                                   float* __restrict__ en2,
                                                   int K) {
    int wave = (int)((blockIdx.x * blockDim.x + threadIdx.x) >> 6);
    int lane = threadIdx.x & 63;
    if (wave >= K) return;
    float v = emb[(size_t)wave * D + lane];
    float s = v * v;
    #pragma unroll
    for (int m = 32; m >= 1; m >>= 1) s += __shfl_xor(s, m, 64);
    float e = v / fmaxf(sqrtf(s), EPS);
    float s2 = e * e;
    #pragma unroll
    for (int m = 32; m >= 1; m >>= 1) s2 += __shfl_xor(s2, m, 64);
    en[(size_t)wave * D + lane] = e;
    if (lane == 0) en2[wave] = s2;
}

// ---------------- Kernel A2: build bf16 A-fragments (layout verified r3/r4) -
// code = t*16 + (l&15), dims = h*32 + (l>>4)*8 + j. 16 B/lane contiguous.
__global__ __launch_bounds__(256) void vq_build_frags(const float* __restrict__ en,
                                                      uint32_t* __restrict__ frags,
                                                      int K) {
    int t = (int)(blockIdx.x * blockDim.x + threadIdx.x);
    int tile = t >> 6, lane = t & 63;
    if (tile >= K / 16) return;
    int code = tile * 16 + (lane & 15);
    int dbase = (lane >> 4) * 8;
    #pragma unroll
    for (int h = 0; h < 2; ++h) {
        const float* p = en + (size_t)code * D + h * 32 + dbase;
        uint4 u;
        u.x = f2bf(p[0]) | (f2bf(p[1]) << 16);
        u.y = f2bf(p[2]) | (f2bf(p[3]) << 16);
        u.z = f2bf(p[4]) | (f2bf(p[5]) << 16);
        u.w = f2bf(p[6]) | (f2bf(p[7]) << 16);
        *(uint4*)(frags + ((size_t)(tile * 2 + h) * 64 + lane) * 4) = u;
    }
}

// ---------------- Kernel B: main ----------------
__global__ __launch_bounds__(256, 4) void vq_main(const float* __restrict__ x,
                                                  const float* __restrict__ en,
                                                  const float* __restrict__ en2g,
                                                  const uint32_t* __restrict__ frags,
                                                  float* __restrict__ out_q,
                                                  float* __restrict__ out_idx,
                                                  double* __restrict__ partials,
                                                  int N, int K) {
    __shared__ float xn[RPB * 64];             // 32 KB, swizzled via xsw()
    __shared__ uint16_t cand[WPB][CAP];        // 6.5 KB, (k<<5)|rloc
    __shared__ int candcnt[WPB];
    __shared__ unsigned long long keys[RPB];   // 1 KB
    __shared__ double red[WPB];
    // total 40.5 KB -> 4 blocks/CU

    const int tid = (int)threadIdx.x;
    const int w = tid >> 6, lane = tid & 63;
    const int rowbase = (int)blockIdx.x * RPB;
    const int NT = K / 16;                     // 128 tiles

    // ---- phase 0 (all LDS below is wave-local; LDS is in-order per wave) ----
    for (int r = 0; r < RPW; ++r) {
        int rb = w * RPW + r;
        float v = x[(size_t)(rowbase + rb) * D + lane];
        float s = v * v;
        #pragma unroll
        for (int m = 32; m >= 1; m >>= 1) s += __shfl_xor(s, m, 64);
        xn[xsw(rb, lane)] = v / fmaxf(sqrtf(s), EPS);   // division: ref fidelity
    }
    if (lane == 0) candcnt[w] = 0;
    if (lane < RPW) keys[w * RPW + lane] = ~0ull;

    // ---- B-fragments in registers (mapping identical to passing r3/r4) ----
    bf16x8 bfr[RG][2];
    #pragma unroll
    for (int g = 0; g < RG; ++g)
        #pragma unroll
        for (int h = 0; h < 2; ++h) {
            int row = w * RPW + g * 16 + (lane & 15);
            int db = h * 32 + ((lane >> 4) * 8);
            union { uint32_t u[4]; bf16x8 v; } cvt;
            #pragma unroll
            for (int j = 0; j < 4; ++j)
                cvt.u[j] = f2bf(xn[xsw(row, db + 2 * j)]) |
                           (f2bf(xn[xsw(row, db + 2 * j + 1)]) << 16);
            bfr[g][h] = cvt.v;
        }

    // ---- single scoring pass, streaming per-row max threshold ----
    // Winner safety: R(k*) >= final_max - 2*delta >= runmax_after(t) - MARGIN.
    float runmax[RG];
    #pragma unroll
    for (int g = 0; g < RG; ++g) runmax[g] = -3.0e38f;
    const f32x4 zero4 = {0.f, 0.f, 0.f, 0.f};

    for (int t = 0; t < NT; ++t) {
        bf16x8 a0 = *(const bf16x8*)(frags + ((size_t)(t * 2 + 0) * 64 + lane) * 4);
        bf16x8 a1 = *(const bf16x8*)(frags + ((size_t)(t * 2 + 1) * 64 + lane) * 4);
        int cb = t * 16 + ((lane >> 4) << 2);
        f32x4 acc[RG];
        #pragma unroll
        for (int g = 0; g < RG; ++g) {
            acc[g] = __builtin_amdgcn_mfma_f32_16x16x32_bf16(a0, bfr[g][0], zero4, 0, 0, 0);
            acc[g] = __builtin_amdgcn_mfma_f32_16x16x32_bf16(a1, bfr[g][1], acc[g], 0, 0, 0);
        }
        #pragma unroll
        for (int g = 0; g < RG; ++g) {
            float m4 = fmaxf(fmaxf(acc[g][0], acc[g][1]), fmaxf(acc[g][2], acc[g][3]));
            float rm = fmaxf(m4, __shfl_xor(m4, 16, 64));   // 4 lanes share a row
            rm = fmaxf(rm, __shfl_xor(rm, 32, 64));
            runmax[g] = fmaxf(runmax[g], rm);
            float tau = runmax[g] - MARGIN;
            if (__any(m4 >= tau)) {                          // rare
                int rloc = g * 16 + (lane & 15);
                #pragma unroll
                for (int q = 0; q < 4; ++q) {
                    if (acc[g][q] >= tau) {
                        int k = cb + q;
                        int slot = atomicAdd(&candcnt[w], 1);
                        if (slot < CAP) {
                            cand[w][slot] = (uint16_t)((k << 5) | rloc);
                        } else {   // overflow fallback: inline exact rescore
                            const float* ev = en + (size_t)k * D;
                            float dot = 0.f;
                            #pragma unroll
                            for (int d0 = 0; d0 < D; ++d0)
                                dot = fmaf(xn[xsw(w * RPW + rloc, d0)], ev[d0], dot);
                            float R = fmaf(-0.5f, en2g[k], dot);
                            uint32_t fb = __builtin_bit_cast(uint32_t, -R);
                            uint32_t ord = (fb & 0x80000000u) ? ~fb : (fb | 0x80000000u);
                            atomicMin(&keys[w * RPW + rloc],
                                      ((unsigned long long)ord << 32) | (uint32_t)k);
                        }
                    }
                }
            }
        }
        if ((t & 15) == 15) __syncthreads();   // loose lockstep -> L1 frag reuse
    }

    // ---- exact fp32 rescore (arithmetic bit-identical to r3/r4) ----
    int cnt = candcnt[w];
    cnt = cnt < CAP ? cnt : CAP;
    for (int base = 0; base < cnt; base += 64) {
        int i = base + lane;
        if (i < cnt) {
            uint32_t e = cand[w][i];
            int k = (int)(e >> 5), rloc = (int)(e & 31u);
            const float* ev = en + (size_t)k * D;
            float dot = 0.f;
            #pragma unroll
            for (int d0 = 0; d0 < D; ++d0)
                dot = fmaf(xn[xsw(w * RPW + rloc, d0)], ev[d0], dot);
            float R = fmaf(-0.5f, en2g[k], dot);
            uint32_t fb = __builtin_bit_cast(uint32_t, -R);   // minimize -R
            uint32_t ord = (fb & 0x80000000u) ? ~fb : (fb | 0x80000000u);
            atomicMin(&keys[w * RPW + rloc],                  // ties -> smaller k
                      ((unsigned long long)ord << 32) | (uint32_t)k);
        }
    }

    // ---- epilogue (wave-local rows; no barrier needed) ----
    float ls = 0.f;
    for (int r = 0; r < RPW; ++r) {
        int rb = w * RPW + r;
        int k = (int)(keys[rb] & 0x7FFull);
        float rn = fmaxf(sqrtf(en2g[k]), EPS);
        float q = en[(size_t)k * D + lane] / rn;       // l2norm(en[k]) exactly
        float a = xn[xsw(rb, lane)];
        float dx = q - a;
        ls = fmaf(dx, dx, ls);
        out_q[(size_t)(rowbase + rb) * D + lane] = a + dx;   // xn + (q - xn)
    }
    if (lane < RPW) out_idx[rowbase + w * RPW + lane] =
        (float)(int)(keys[w * RPW + lane] & 0x7FFull);
    #pragma unroll
    for (int m = 32; m >= 1; m >>= 1) ls += __shfl_xor(ls, m, 64);
    if (lane == 0) red[w] = (double)ls;
    __syncthreads();
    if (tid == 0) {
        double s = 0.0;
        #pragma unroll
        for (int i = 0; i < WPB; ++i) s += red[i];
        partials[blockIdx.x] = s;
    }
}

// ---------------- Kernel C: finalize loss ----------------
__global__ __launch_bounds__(512) void vq_finalize(const double* __restrict__ partials,
                                                   int nb, float* __restrict__ loss_out,
                                                   int N) {
    __shared__ double red[512];
    int t = (int)threadIdx.x;
    double s = 0.0;
    for (int i = t; i < nb; i += 512) s += partials[i];
    red[t] = s;
    __syncthreads();
    #pragma unroll
    for (int off = 256; off >= 1; off >>= 1) {
        if (t < off) red[t] += red[t + off];
        __syncthreads();
    }
    if (t == 0) {
        double mean = red[0] / ((double)N * (double)D);
        loss_out[0] = (float)(mean * 1.25);   // q_loss + 0.25*e_loss (identical)
    }
}

extern "C" void kernel_launch(void* const* d_in, const int* in_sizes, int n_in,
                              void* d_out, int out_size, void* d_ws, size_t ws_size,
                              hipStream_t stream) {
    const float* x   = (const float*)d_in[0];
    const float* emb = (const float*)d_in[1];
    int N = in_sizes[0] / D;
    int K = in_sizes[1] / D;

    float* out      = (float*)d_out;
    float* out_q    = out;
    float* loss_out = out + (size_t)N * D;
    float* out_idx  = out + (size_t)N * D + 1;

    char* ws = (char*)d_ws;
    double*   partials = (double*)ws;                       // 8 KB
    float*    en2      = (float*)(ws + 8192);               // 8 KB
    float*    en       = (float*)(ws + 16384);              // 512 KB
    uint32_t* frags    = (uint32_t*)(ws + 540672);          // 256 KB

    vq_norm_emb<<<(K + 3) / 4, 256, 0, stream>>>(emb, en, en2, K);
    vq_build_frags<<<(K / 16 * 64 + 255) / 256, 256, 0, stream>>>(en, frags, K);

    int nbB = N / RPB;   // 1024 blocks = exactly 4/CU resident, no tail
    vq_main<<<nbB, 256, 0, stream>>>(x, en, en2, frags, out_q, out_idx,
                                     partials, N, K);
    vq_finalize<<<1, 512, 0, stream>>>(partials, nbB, loss_out, N);
}

// Round 7
// 184.235 us; speedup vs baseline: 1.8841x; 1.0612x over previous
//
#include <hip/hip_runtime.h>
#include <math.h>
#include <stdint.h>

// VectorQuantizer on MI355X (gfx950). N=131072, D=64, K=2048, fp32.
// Round 6 (resubmit; GPU never acquired): r5 + (1) ping-pong register
// prefetch of frag tiles (kills the correlated vmcnt(0) stall-on-use that
// left both pipes ~55% idle), and (2) launch fusion 4->2 kernels (prep =
// norm+fragbuild; loss via one float atomicAdd per block).
// All numerically load-bearing code is bit-identical to the r5 PASS.
// out: [N*D] quantized_st | [1] loss | [N] idx (as float)
// ws: [8192] f32 en2[K] | [16384] f32 en[K*64] | [540672] u32 frags[K*32]

#define D 64
#define EPS 1e-12f
#define WPB 4              // waves per block (vq_main)
#define RG 2               // row-groups (16 rows) per wave
#define RPW (RG * 16)      // 32 rows per wave
#define RPB (WPB * RPW)    // 128 rows per block
#define CAP 832            // u16 candidate entries per wave
#define MARGIN 0.010f      // > 2*delta; delta = bf16 dot err (<=3.9e-3) + 1e-6

typedef short bf16x8 __attribute__((ext_vector_type(8)));
typedef float f32x4 __attribute__((ext_vector_type(4)));

__device__ __forceinline__ uint32_t f2bf(float f) {   // RNE f32->bf16 (finite)
    uint32_t u = __builtin_bit_cast(uint32_t, f);
    return (u + 0x7FFFu + ((u >> 16) & 1u)) >> 16;
}
// xn LDS swizzle: float4-slot XOR by row&7 -> conflict-free frag/row access
__device__ __forceinline__ int xsw(int row, int d) {
    return row * 64 + ((((d >> 2) ^ (row & 7)) << 2) | (d & 3));
}

// ---------- Kernel 1: normalize codebook + build bf16 A-fragments ----------
// One block per 16-code tile; wave w normalizes code row tile*16+w (reduce
// chain bit-identical to r3/r4/r5); wave 0 then packs the tile's fragments
// (layout byte-identical to the verified vq_build_frags). Also zeroes the
// loss accumulator slot (block 0) for vq_main's atomicAdd.
__global__ __launch_bounds__(1024) void vq_prep(const float* __restrict__ emb,
                                                float* __restrict__ en,
                                                float* __restrict__ en2,
                                                uint32_t* __restrict__ frags,
                                                float* __restrict__ loss_out,
                                                int K) {
    __shared__ float sh[16][64];
    int w = (int)(threadIdx.x >> 6), lane = (int)(threadIdx.x & 63);
    int tile = (int)blockIdx.x;
    int row = tile * 16 + w;
    if (row < K) {
        float v = emb[(size_t)row * D + lane];
        float s = v * v;
        #pragma unroll
        for (int m = 32; m >= 1; m >>= 1) s += __shfl_xor(s, m, 64);
        float e = v / fmaxf(sqrtf(s), EPS);      // division: F.normalize fidelity
        float s2 = e * e;
        #pragma unroll
        for (int m = 32; m >= 1; m >>= 1) s2 += __shfl_xor(s2, m, 64);
        en[(size_t)row * D + lane] = e;
        if (lane == 0) en2[row] = s2;
        sh[w][lane] = e;
    }
    if (blockIdx.x == 0 && threadIdx.x == 0) loss_out[0] = 0.f;
    __syncthreads();
    if (w == 0) {                                // wave 0 packs the tile
        int cl = lane & 15, dbase = (lane >> 4) * 8;
        #pragma unroll
        for (int h = 0; h < 2; ++h) {
            const float* p = &sh[cl][h * 32 + dbase];
            uint4 u;
            u.x = f2bf(p[0]) | (f2bf(p[1]) << 16);
            u.y = f2bf(p[2]) | (f2bf(p[3]) << 16);
            u.z = f2bf(p[4]) | (f2bf(p[5]) << 16);
            u.w = f2bf(p[6]) | (f2bf(p[7]) << 16);
            *(uint4*)(frags + ((size_t)(tile * 2 + h) * 64 + lane) * 4) = u;
        }
    }
}

// ---------------- Kernel 2: main ----------------
__global__ __launch_bounds__(256, 4) void vq_main(const float* __restrict__ x,
                                                  const float* __restrict__ en,
                                                  const float* __restrict__ en2g,
                                                  const uint32_t* __restrict__ frags,
                                                  float* __restrict__ out_q,
                                                  float* __restrict__ out_idx,
                                                  float* __restrict__ loss_out,
                                                  int N, int K) {
    __shared__ float xn[RPB * 64];             // 32 KB, swizzled via xsw()
    __shared__ uint16_t cand[WPB][CAP];        // 6.5 KB, (k<<5)|rloc
    __shared__ int candcnt[WPB];
    __shared__ unsigned long long keys[RPB];   // 1 KB
    __shared__ double red[WPB];
    // total ~39.7 KB -> 4 blocks/CU

    const int tid = (int)threadIdx.x;
    const int w = tid >> 6, lane = tid & 63;
    const int rowbase = (int)blockIdx.x * RPB;
    const int NT = K / 16;                     // 128 tiles
    const int lq = (lane >> 4) << 2;           // k-quad base within tile

    // ---- phase 0 (bit-identical to r5) ----
    for (int r = 0; r < RPW; ++r) {
        int rb = w * RPW + r;
        float v = x[(size_t)(rowbase + rb) * D + lane];
        float s = v * v;
        #pragma unroll
        for (int m = 32; m >= 1; m >>= 1) s += __shfl_xor(s, m, 64);
        xn[xsw(rb, lane)] = v / fmaxf(sqrtf(s), EPS);
    }
    if (lane == 0) candcnt[w] = 0;
    if (lane < RPW) keys[w * RPW + lane] = ~0ull;

    // ---- B-fragments in registers (mapping verified r3/r4/r5) ----
    bf16x8 bfr[RG][2];
    #pragma unroll
    for (int g = 0; g < RG; ++g)
        #pragma unroll
        for (int h = 0; h < 2; ++h) {
            int row = w * RPW + g * 16 + (lane & 15);
            int db = h * 32 + ((lane >> 4) * 8);
            union { uint32_t u[4]; bf16x8 v; } cvt;
            #pragma unroll
            for (int j = 0; j < 4; ++j)
                cvt.u[j] = f2bf(xn[xsw(row, db + 2 * j)]) |
                           (f2bf(xn[xsw(row, db + 2 * j + 1)]) << 16);
            bfr[g][h] = cvt.v;
        }

    // ---- single scoring pass, streaming per-row max threshold (as r5) ----
    float runmax[RG];
    #pragma unroll
    for (int g = 0; g < RG; ++g) runmax[g] = -3.0e38f;
    const f32x4 zero4 = {0.f, 0.f, 0.f, 0.f};

    auto score = [&](int T, bf16x8 A0, bf16x8 A1) {
        int cb = T * 16 + lq;
        f32x4 acc[RG];
        #pragma unroll
        for (int g = 0; g < RG; ++g) {
            acc[g] = __builtin_amdgcn_mfma_f32_16x16x32_bf16(A0, bfr[g][0], zero4, 0, 0, 0);
            acc[g] = __builtin_amdgcn_mfma_f32_16x16x32_bf16(A1, bfr[g][1], acc[g], 0, 0, 0);
        }
        #pragma unroll
        for (int g = 0; g < RG; ++g) {
            float m4 = fmaxf(fmaxf(acc[g][0], acc[g][1]), fmaxf(acc[g][2], acc[g][3]));
            float rm = fmaxf(m4, __shfl_xor(m4, 16, 64));   // 4 lanes share a row
            rm = fmaxf(rm, __shfl_xor(rm, 32, 64));
            runmax[g] = fmaxf(runmax[g], rm);
            float tau = runmax[g] - MARGIN;
            if (__any(m4 >= tau)) {                          // rare
                int rloc = g * 16 + (lane & 15);
                #pragma unroll
                for (int q = 0; q < 4; ++q) {
                    if (acc[g][q] >= tau) {
                        int k = cb + q;
                        int slot = atomicAdd(&candcnt[w], 1);
                        if (slot < CAP) {
                            cand[w][slot] = (uint16_t)((k << 5) | rloc);
                        } else {   // overflow fallback: inline exact rescore
                            const float* ev = en + (size_t)k * D;
                            float dot = 0.f;
                            #pragma unroll
                            for (int d0 = 0; d0 < D; ++d0)
                                dot = fmaf(xn[xsw(w * RPW + rloc, d0)], ev[d0], dot);
                            float R = fmaf(-0.5f, en2g[k], dot);
                            uint32_t fb = __builtin_bit_cast(uint32_t, -R);
                            uint32_t ord = (fb & 0x80000000u) ? ~fb : (fb | 0x80000000u);
                            atomicMin(&keys[w * RPW + rloc],
                                      ((unsigned long long)ord << 32) | (uint32_t)k);
                        }
                    }
                }
            }
        }
    };

    // Ping-pong prefetch: frag loads issued >=1 tile (~350 issue-cyc/SIMD)
    // ahead of use, so L2 latency hides under MFMA+VALU instead of stalling
    // all lockstep waves at vmcnt(0).
    const bf16x8* p = (const bf16x8*)frags + lane;   // 16 B/lane, tile stride 128
    bf16x8 A0 = p[0], A1 = p[64];
    for (int t = 0; t < NT; t += 2) {
        bf16x8 B0 = p[128], B1 = p[192];             // prefetch tile t+1
        score(t, A0, A1);
        if (t + 2 < NT) { A0 = p[256]; A1 = p[320]; } // prefetch tile t+2
        score(t + 1, B0, B1);
        p += 256;
        if (((t + 1) & 15) == 15) __syncthreads();   // loose lockstep (as r5)
    }

    // ---- exact fp32 rescore (arithmetic bit-identical to r3/r4/r5) ----
    int cnt = candcnt[w];
    cnt = cnt < CAP ? cnt : CAP;
    for (int base = 0; base < cnt; base += 64) {
        int i = base + lane;
        if (i < cnt) {
            uint32_t e = cand[w][i];
            int k = (int)(e >> 5), rloc = (int)(e & 31u);
            const float* ev = en + (size_t)k * D;
            float dot = 0.f;
            #pragma unroll
            for (int d0 = 0; d0 < D; ++d0)
                dot = fmaf(xn[xsw(w * RPW + rloc, d0)], ev[d0], dot);
            float R = fmaf(-0.5f, en2g[k], dot);
            uint32_t fb = __builtin_bit_cast(uint32_t, -R);   // minimize -R
            uint32_t ord = (fb & 0x80000000u) ? ~fb : (fb | 0x80000000u);
            atomicMin(&keys[w * RPW + rloc],                  // ties -> smaller k
                      ((unsigned long long)ord << 32) | (uint32_t)k);
        }
    }

    // ---- epilogue (wave-local rows) ----
    float ls = 0.f;
    for (int r = 0; r < RPW; ++r) {
        int rb = w * RPW + r;
        int k = (int)(keys[rb] & 0x7FFull);
        float rn = fmaxf(sqrtf(en2g[k]), EPS);
        float q = en[(size_t)k * D + lane] / rn;       // l2norm(en[k]) exactly
        float a = xn[xsw(rb, lane)];
        float dx = q - a;
        ls = fmaf(dx, dx, ls);
        out_q[(size_t)(rowbase + rb) * D + lane] = a + dx;   // xn + (q - xn)
    }
    if (lane < RPW) out_idx[rowbase + w * RPW + lane] =
        (float)(int)(keys[w * RPW + lane] & 0x7FFull);
    #pragma unroll
    for (int m = 32; m >= 1; m >>= 1) ls += __shfl_xor(ls, m, 64);
    if (lane == 0) red[w] = (double)ls;
    __syncthreads();
    if (tid == 0) {
        double s = 0.0;
        #pragma unroll
        for (int i = 0; i < WPB; ++i) s += red[i];
        // loss = 1.25 * sum/(N*D); block contribution ~3e-4, fp32 atomic
        // accumulation error ~1e-6 << tolerance. Slot zeroed by vq_prep.
        atomicAdd(loss_out, (float)(s * (1.25 / ((double)N * (double)D))));
    }
}

extern "C" void kernel_launch(void* const* d_in, const int* in_sizes, int n_in,
                              void* d_out, int out_size, void* d_ws, size_t ws_size,
                              hipStream_t stream) {
    const float* x   = (const float*)d_in[0];
    const float* emb = (const float*)d_in[1];
    int N = in_sizes[0] / D;
    int K = in_sizes[1] / D;

    float* out      = (float*)d_out;
    float* out_q    = out;
    float* loss_out = out + (size_t)N * D;
    float* out_idx  = out + (size_t)N * D + 1;

    char* ws = (char*)d_ws;
    float*    en2   = (float*)(ws + 8192);               // 8 KB
    float*    en    = (float*)(ws + 16384);              // 512 KB
    uint32_t* frags = (uint32_t*)(ws + 540672);          // 256 KB

    vq_prep<<<K / 16, 1024, 0, stream>>>(emb, en, en2, frags, loss_out, K);
    vq_main<<<N / RPB, 256, 0, stream>>>(x, en, en2, frags, out_q, out_idx,
                                         loss_out, N, K);
}

// Round 8
// 183.984 us; speedup vs baseline: 1.8867x; 1.0014x over previous
//
#include <hip/hip_runtime.h>
#include <math.h>
#include <stdint.h>

// VectorQuantizer on MI355X (gfx950). N=131072, D=64, K=2048, fp32.
// Round 8: two-pass scan. r7 post-mortem: per-tile shfl-reduce chains +
// 76%-trigger-rate candidate collection were ~5x the static VALU estimate.
// Pass 1 = pure MFMA + independent per-lane fmax (no shfl/atomic/branch).
// Pass 2 = recompute (bit-identical MFMA) + collect vs FINAL tau
// (trigger ~17% of tiles, cands ~1.5/row). Rescore/epilogue bit-identical
// to the r5/r7 PASSES.
// out: [N*D] quantized_st | [1] loss | [N] idx (as float)
// ws: [8192] f32 en2[K] | [16384] f32 en[K*64] | [540672] u32 frags[K*32]

#define D 64
#define EPS 1e-12f
#define WPB 4              // waves per block (vq_main)
#define RG 2               // row-groups (16 rows) per wave
#define RPW (RG * 16)      // 32 rows per wave
#define RPB (WPB * RPW)    // 128 rows per block
#define CAP 832            // u16 candidate entries per wave
#define MARGIN 0.010f      // > 2*delta; delta = bf16 dot err (<=3.9e-3) + 1e-6

typedef short bf16x8 __attribute__((ext_vector_type(8)));
typedef float f32x4 __attribute__((ext_vector_type(4)));

__device__ __forceinline__ uint32_t f2bf(float f) {   // RNE f32->bf16 (finite)
    uint32_t u = __builtin_bit_cast(uint32_t, f);
    return (u + 0x7FFFu + ((u >> 16) & 1u)) >> 16;
}
// xn LDS swizzle: float4-slot XOR by row&7 -> conflict-free frag/row access
__device__ __forceinline__ int xsw(int row, int d) {
    return row * 64 + ((((d >> 2) ^ (row & 7)) << 2) | (d & 3));
}

// ---------- Kernel 1: normalize codebook + build bf16 A-fragments ----------
// (verified r7) One block per 16-code tile; wave w normalizes code row
// tile*16+w; wave 0 packs fragments; block 0 zeroes the loss slot.
__global__ __launch_bounds__(1024) void vq_prep(const float* __restrict__ emb,
                                                float* __restrict__ en,
                                                float* __restrict__ en2,
                                                uint32_t* __restrict__ frags,
                                                float* __restrict__ loss_out,
                                                int K) {
    __shared__ float sh[16][64];
    int w = (int)(threadIdx.x >> 6), lane = (int)(threadIdx.x & 63);
    int tile = (int)blockIdx.x;
    int row = tile * 16 + w;
    if (row < K) {
        float v = emb[(size_t)row * D + lane];
        float s = v * v;
        #pragma unroll
        for (int m = 32; m >= 1; m >>= 1) s += __shfl_xor(s, m, 64);
        float e = v / fmaxf(sqrtf(s), EPS);      // division: F.normalize fidelity
        float s2 = e * e;
        #pragma unroll
        for (int m = 32; m >= 1; m >>= 1) s2 += __shfl_xor(s2, m, 64);
        en[(size_t)row * D + lane] = e;
        if (lane == 0) en2[row] = s2;
        sh[w][lane] = e;
    }
    if (blockIdx.x == 0 && threadIdx.x == 0) loss_out[0] = 0.f;
    __syncthreads();
    if (w == 0) {                                // wave 0 packs the tile
        int cl = lane & 15, dbase = (lane >> 4) * 8;
        #pragma unroll
        for (int h = 0; h < 2; ++h) {
            const float* p = &sh[cl][h * 32 + dbase];
            uint4 u;
            u.x = f2bf(p[0]) | (f2bf(p[1]) << 16);
            u.y = f2bf(p[2]) | (f2bf(p[3]) << 16);
            u.z = f2bf(p[4]) | (f2bf(p[5]) << 16);
            u.w = f2bf(p[6]) | (f2bf(p[7]) << 16);
            *(uint4*)(frags + ((size_t)(tile * 2 + h) * 64 + lane) * 4) = u;
        }
    }
}

// ---------------- Kernel 2: main ----------------
__global__ __launch_bounds__(256, 4) void vq_main(const float* __restrict__ x,
                                                  const float* __restrict__ en,
                                                  const float* __restrict__ en2g,
                                                  const uint32_t* __restrict__ frags,
                                                  float* __restrict__ out_q,
                                                  float* __restrict__ out_idx,
                                                  float* __restrict__ loss_out,
                                                  int N, int K) {
    __shared__ float xn[RPB * 64];             // 32 KB, swizzled via xsw()
    __shared__ uint16_t cand[WPB][CAP];        // 6.5 KB, (k<<5)|rloc
    __shared__ int candcnt[WPB];
    __shared__ unsigned long long keys[RPB];   // 1 KB
    __shared__ double red[WPB];
    // total ~39.7 KB -> 4 blocks/CU

    const int tid = (int)threadIdx.x;
    const int w = tid >> 6, lane = tid & 63;
    const int rowbase = (int)blockIdx.x * RPB;
    const int NT = K / 16;                     // 128 tiles
    const int lq = (lane >> 4) << 2;           // k-quad base within tile

    // ---- phase 0 (bit-identical to r5/r7) ----
    for (int r = 0; r < RPW; ++r) {
        int rb = w * RPW + r;
        float v = x[(size_t)(rowbase + rb) * D + lane];
        float s = v * v;
        #pragma unroll
        for (int m = 32; m >= 1; m >>= 1) s += __shfl_xor(s, m, 64);
        xn[xsw(rb, lane)] = v / fmaxf(sqrtf(s), EPS);
    }
    if (lane == 0) candcnt[w] = 0;
    if (lane < RPW) keys[w * RPW + lane] = ~0ull;

    // ---- B-fragments in registers (mapping verified r3-r7) ----
    bf16x8 bfr[RG][2];
    #pragma unroll
    for (int g = 0; g < RG; ++g)
        #pragma unroll
        for (int h = 0; h < 2; ++h) {
            int row = w * RPW + g * 16 + (lane & 15);
            int db = h * 32 + ((lane >> 4) * 8);
            union { uint32_t u[4]; bf16x8 v; } cvt;
            #pragma unroll
            for (int j = 0; j < 4; ++j)
                cvt.u[j] = f2bf(xn[xsw(row, db + 2 * j)]) |
                           (f2bf(xn[xsw(row, db + 2 * j + 1)]) << 16);
            bfr[g][h] = cvt.v;
        }

    const f32x4 zero4 = {0.f, 0.f, 0.f, 0.f};
    const bf16x8* fb = (const bf16x8*)frags + lane;  // 16 B/lane, tile stride 128

    // ======== PASS 1: lean max scan (no shfl, no atomics, no branches) ======
    // 8 independent per-lane fmax chains; MFMA results are deterministic, so
    // pass 2's recompute is bit-identical and the threshold test is sound.
    f32x4 rmax[RG];
    #pragma unroll
    for (int g = 0; g < RG; ++g) rmax[g] = {-3.0e38f, -3.0e38f, -3.0e38f, -3.0e38f};
    {
        const bf16x8* p = fb;
        bf16x8 A0 = p[0], A1 = p[64];
        for (int t = 0; t < NT; t += 2) {
            bf16x8 B0 = p[128], B1 = p[192];             // prefetch tile t+1
            #pragma unroll
            for (int g = 0; g < RG; ++g) {
                f32x4 acc = __builtin_amdgcn_mfma_f32_16x16x32_bf16(A0, bfr[g][0], zero4, 0, 0, 0);
                acc = __builtin_amdgcn_mfma_f32_16x16x32_bf16(A1, bfr[g][1], acc, 0, 0, 0);
                #pragma unroll
                for (int q = 0; q < 4; ++q) rmax[g][q] = fmaxf(rmax[g][q], acc[q]);
            }
            if (t + 2 < NT) { A0 = p[256]; A1 = p[320]; } // prefetch tile t+2
            #pragma unroll
            for (int g = 0; g < RG; ++g) {
                f32x4 acc = __builtin_amdgcn_mfma_f32_16x16x32_bf16(B0, bfr[g][0], zero4, 0, 0, 0);
                acc = __builtin_amdgcn_mfma_f32_16x16x32_bf16(B1, bfr[g][1], acc, 0, 0, 0);
                #pragma unroll
                for (int q = 0; q < 4; ++q) rmax[g][q] = fmaxf(rmax[g][q], acc[q]);
            }
            p += 256;
            if (((t + 1) & 15) == 15) __syncthreads();   // loose lockstep: L1 reuse
        }
    }
    // final row tau: reduce 4 slots + 4 lanes sharing a row (lane^16, lane^32)
    float tau[RG];
    #pragma unroll
    for (int g = 0; g < RG; ++g) {
        float m = fmaxf(fmaxf(rmax[g][0], rmax[g][1]), fmaxf(rmax[g][2], rmax[g][3]));
        m = fmaxf(m, __shfl_xor(m, 16, 64));
        m = fmaxf(m, __shfl_xor(m, 32, 64));
        tau[g] = m - MARGIN;
    }

    // ======== PASS 2: recompute + collect vs final tau (trigger ~17%) =======
    {
        const bf16x8* p = fb;
        bf16x8 A0 = p[0], A1 = p[64];
        for (int t = 0; t < NT; ++t) {
            bf16x8 nA0, nA1;
            if (t + 1 < NT) { nA0 = p[128]; nA1 = p[192]; }
            int cb = t * 16 + lq;
            #pragma unroll
            for (int g = 0; g < RG; ++g) {
                f32x4 acc = __builtin_amdgcn_mfma_f32_16x16x32_bf16(A0, bfr[g][0], zero4, 0, 0, 0);
                acc = __builtin_amdgcn_mfma_f32_16x16x32_bf16(A1, bfr[g][1], acc, 0, 0, 0);
                float m4 = fmaxf(fmaxf(acc[0], acc[1]), fmaxf(acc[2], acc[3]));
                if (__any(m4 >= tau[g])) {                // ~17% of tiles
                    int rloc = g * 16 + (lane & 15);
                    #pragma unroll
                    for (int q = 0; q < 4; ++q) {
                        if (acc[q] >= tau[g]) {
                            int k = cb + q;
                            int slot = atomicAdd(&candcnt[w], 1);
                            if (slot < CAP) {
                                cand[w][slot] = (uint16_t)((k << 5) | rloc);
                            } else {   // overflow fallback: inline exact rescore
                                const float* ev = en + (size_t)k * D;
                                float dot = 0.f;
                                #pragma unroll
                                for (int d0 = 0; d0 < D; ++d0)
                                    dot = fmaf(xn[xsw(w * RPW + rloc, d0)], ev[d0], dot);
                                float R = fmaf(-0.5f, en2g[k], dot);
                                uint32_t fbt = __builtin_bit_cast(uint32_t, -R);
                                uint32_t ord = (fbt & 0x80000000u) ? ~fbt : (fbt | 0x80000000u);
                                atomicMin(&keys[w * RPW + rloc],
                                          ((unsigned long long)ord << 32) | (uint32_t)k);
                            }
                        }
                    }
                }
            }
            A0 = nA0; A1 = nA1;
            p += 128;
            if ((t & 15) == 15) __syncthreads();         // loose lockstep
        }
    }

    // ---- exact fp32 rescore (arithmetic bit-identical to r3-r7) ----
    int cnt = candcnt[w];
    cnt = cnt < CAP ? cnt : CAP;
    for (int base = 0; base < cnt; base += 64) {
        int i = base + lane;
        if (i < cnt) {
            uint32_t e = cand[w][i];
            int k = (int)(e >> 5), rloc = (int)(e & 31u);
            const float* ev = en + (size_t)k * D;
            float dot = 0.f;
            #pragma unroll
            for (int d0 = 0; d0 < D; ++d0)
                dot = fmaf(xn[xsw(w * RPW + rloc, d0)], ev[d0], dot);
            float R = fmaf(-0.5f, en2g[k], dot);
            uint32_t fbt = __builtin_bit_cast(uint32_t, -R);  // minimize -R
            uint32_t ord = (fbt & 0x80000000u) ? ~fbt : (fbt | 0x80000000u);
            atomicMin(&keys[w * RPW + rloc],                  // ties -> smaller k
                      ((unsigned long long)ord << 32) | (uint32_t)k);
        }
    }

    // ---- epilogue (wave-local rows; bit-identical to r5/r7) ----
    float ls = 0.f;
    for (int r = 0; r < RPW; ++r) {
        int rb = w * RPW + r;
        int k = (int)(keys[rb] & 0x7FFull);
        float rn = fmaxf(sqrtf(en2g[k]), EPS);
        float q = en[(size_t)k * D + lane] / rn;       // l2norm(en[k]) exactly
        float a = xn[xsw(rb, lane)];
        float dx = q - a;
        ls = fmaf(dx, dx, ls);
        out_q[(size_t)(rowbase + rb) * D + lane] = a + dx;   // xn + (q - xn)
    }
    if (lane < RPW) out_idx[rowbase + w * RPW + lane] =
        (float)(int)(keys[w * RPW + lane] & 0x7FFull);
    #pragma unroll
    for (int m = 32; m >= 1; m >>= 1) ls += __shfl_xor(ls, m, 64);
    if (lane == 0) red[w] = (double)ls;
    __syncthreads();
    if (tid == 0) {
        double s = 0.0;
        #pragma unroll
        for (int i = 0; i < WPB; ++i) s += red[i];
        // loss = 1.25 * sum/(N*D); fp32 atomic accumulation (verified r7)
        atomicAdd(loss_out, (float)(s * (1.25 / ((double)N * (double)D))));
    }
}

extern "C" void kernel_launch(void* const* d_in, const int* in_sizes, int n_in,
                              void* d_out, int out_size, void* d_ws, size_t ws_size,
                              hipStream_t stream) {
    const float* x   = (const float*)d_in[0];
    const float* emb = (const float*)d_in[1];
    int N = in_sizes[0] / D;
    int K = in_sizes[1] / D;

    float* out      = (float*)d_out;
    float* out_q    = out;
    float* loss_out = out + (size_t)N * D;
    float* out_idx  = out + (size_t)N * D + 1;

    char* ws = (char*)d_ws;
    float*    en2   = (float*)(ws + 8192);               // 8 KB
    float*    en    = (float*)(ws + 16384);              // 512 KB
    uint32_t* frags = (uint32_t*)(ws + 540672);          // 256 KB

    vq_prep<<<K / 16, 1024, 0, stream>>>(emb, en, en2, frags, loss_out, K);
    vq_main<<<N / RPB, 256, 0, stream>>>(x, en, en2, frags, out_q, out_idx,
                                         loss_out, N, K);
}